// Round 1
// baseline (560.408 us; speedup 1.0000x reference)
//
#include <hip/hip_runtime.h>

// Problem constants (fixed by setup_inputs)
#define DIM 512
#define NQ 64
#define BATCH 2048
#define MT 64            // batch rows per block in GEMM
#define APAD 520         // LDS row stride (bf16 elems) for A tile: 520*2=1040B, 16B-aligned, bank-friendly

typedef __bf16  bf16x8  __attribute__((ext_vector_type(8)));
typedef float   floatx4 __attribute__((ext_vector_type(4)));

static __device__ inline unsigned short f2bf(float f) {
    unsigned int u = __float_as_uint(f);
    unsigned int r = (u + 0x7fffu + ((u >> 16) & 1u)) >> 16;  // RNE
    return (unsigned short)r;
}

__global__ void hsq_zero_kernel(float* p) { p[threadIdx.x] = 0.0f; }

// Expand q_coefs (n_mono, 64) into W[k][e][d] (bf16, d contiguous) with the
// m_scaled scaling (2 on diag, sqrt2 off-diag), fusing norm2[k] = sum q^2.
__global__ void hsq_expand_kernel(const float* __restrict__ qc,
                                  unsigned short* __restrict__ W,
                                  float* __restrict__ norm2) {
    const int e  = blockIdx.x;          // 0..511
    const int kb = blockIdx.y;          // 0..15
    const int kq = threadIdx.x >> 6;    // 0..3 (one wave per kq)
    const int k  = kb * 4 + kq;
    const int dl = threadIdx.x & 63;

    float nacc = 0.0f;
#pragma unroll
    for (int it = 0; it < 8; ++it) {
        const int d = it * 64 + dl;
        const int i = d < e ? d : e;
        const int j = d < e ? e : d;
        const int idx = i * DIM - ((i * (i - 1)) >> 1) + (j - i);
        const float cv = qc[idx * NQ + k];
        const float s = (d == e) ? 2.0f : 1.41421356237309515f;
        W[((size_t)(k * DIM + e)) * DIM + d] = f2bf(s * cv);
        if (d >= e) nacc += cv * cv;    // counts each monomial exactly once over grid
    }
#pragma unroll
    for (int off = 1; off < 64; off <<= 1) nacc += __shfl_xor(nacc, off);
    if (dl == 0) atomicAdd(&norm2[k], nacc);
}

// Main fused kernel: per block = (64 batch rows, one quadric k).
// G = P_tile (64x512) * M_k (512x512) via mfma_f32_16x16x32_bf16,
// epilogue reduces over e to produce scores directly.
__global__ __launch_bounds__(256, 2)
void hsq_gemm_kernel(const float* __restrict__ points,
                     const unsigned short* __restrict__ W,
                     const float* __restrict__ l_coefs,
                     const float* __restrict__ free_coefs,
                     const float* __restrict__ norm2,
                     float* __restrict__ out) {
    const int mb = blockIdx.x;   // 0..31  batch tile
    const int k  = blockIdx.y;   // 0..63  quadric
    const int tid  = threadIdx.x;
    const int wid  = tid >> 6;   // 0..3, wave covers e in [wid*128, wid*128+128)
    const int lane = tid & 63;
    const int c    = lane & 15;  // MFMA col / A row index
    const int quad = lane >> 4;  // MFMA k-block / D row-block

    __shared__ unsigned short As[MT * APAD];   // 66560 B, bf16 P tile
    __shared__ float red[4][MT][2];            // per-wave partial (pv, pg) per row

    // ---- Stage A once: 64 rows x 512 cols fp32 -> bf16 LDS (float4 loads) ----
    {
        const float* src = points + (size_t)mb * MT * DIM;
#pragma unroll
        for (int it = 0; it < 32; ++it) {
            const int lin4 = it * 256 + tid;       // over 64*128 float4s
            const int r  = lin4 >> 7;
            const int c4 = lin4 & 127;
            const float4 v = *reinterpret_cast<const float4*>(src + ((size_t)r * DIM + c4 * 4));
            unsigned short* dst = &As[r * APAD + c4 * 4];
            dst[0] = f2bf(v.x); dst[1] = f2bf(v.y);
            dst[2] = f2bf(v.z); dst[3] = f2bf(v.w);
        }
    }
    __syncthreads();

    // ---- K-loop: no barriers. A from LDS, B frags direct from global W. ----
    floatx4 acc[4][8];
#pragma unroll
    for (int mt = 0; mt < 4; ++mt)
#pragma unroll
        for (int nt = 0; nt < 8; ++nt)
            acc[mt][nt] = (floatx4){0.f, 0.f, 0.f, 0.f};

    const unsigned short* Wk = W + (size_t)k * DIM * DIM;

    for (int ks = 0; ks < 16; ++ks) {
        const int d0 = ks * 32;
        bf16x8 af[4];
#pragma unroll
        for (int mt = 0; mt < 4; ++mt)
            af[mt] = *reinterpret_cast<const bf16x8*>(&As[(mt * 16 + c) * APAD + d0 + quad * 8]);
        bf16x8 bf[8];
#pragma unroll
        for (int nt = 0; nt < 8; ++nt) {
            const int e = wid * 128 + nt * 16 + c;
            bf[nt] = *reinterpret_cast<const bf16x8*>(Wk + (size_t)e * DIM + d0 + quad * 8);
        }
#pragma unroll
        for (int mt = 0; mt < 4; ++mt)
#pragma unroll
            for (int nt = 0; nt < 8; ++nt)
                acc[mt][nt] = __builtin_amdgcn_mfma_f32_16x16x32_bf16(af[mt], bf[nt], acc[mt][nt], 0, 0, 0);
    }

    // ---- Epilogue: per-row reductions over this wave's 128 e-columns ----
    // pv = sum_e p[b,e]*(0.5*g + l[e,k]);  pg = sum_e (g + l[e,k])^2
#pragma unroll
    for (int mt = 0; mt < 4; ++mt) {
        float pv[4] = {0.f, 0.f, 0.f, 0.f};
        float pg[4] = {0.f, 0.f, 0.f, 0.f};
#pragma unroll
        for (int nt = 0; nt < 8; ++nt) {
            const int e = wid * 128 + nt * 16 + c;
            const float l = l_coefs[e * NQ + k];
            const int rowbase = mb * MT + mt * 16 + quad * 4;
#pragma unroll
            for (int r = 0; r < 4; ++r) {
                const float p = points[(size_t)(rowbase + r) * DIM + e];
                const float g = acc[mt][nt][r];
                pv[r] += p * (0.5f * g + l);
                const float qg = g + l;
                pg[r] += qg * qg;
            }
        }
#pragma unroll
        for (int r = 0; r < 4; ++r) {
#pragma unroll
            for (int off = 1; off < 16; off <<= 1) {
                pv[r] += __shfl_xor(pv[r], off);
                pg[r] += __shfl_xor(pg[r], off);
            }
            if (c == 0) {
                const int row = mt * 16 + quad * 4 + r;
                red[wid][row][0] = pv[r];
                red[wid][row][1] = pg[r];
            }
        }
    }
    __syncthreads();

    if (tid < MT) {
        const int row = tid;
        float v = 0.f, g = 0.f;
#pragma unroll
        for (int w = 0; w < 4; ++w) { v += red[w][row][0]; g += red[w][row][1]; }
        const float vals = fabsf(v + free_coefs[k]);
        const float nrm  = sqrtf(norm2[k]);
        const float sc   = (sqrtf(0.25f * g + vals * nrm) - 0.5f * sqrtf(g)) / nrm;
        out[(size_t)(mb * MT + row) * NQ + k] = sc;
    }
}

extern "C" void kernel_launch(void* const* d_in, const int* in_sizes, int n_in,
                              void* d_out, int out_size, void* d_ws, size_t ws_size,
                              hipStream_t stream) {
    const float* points     = (const float*)d_in[0];  // (2048, 512)
    const float* q_coefs    = (const float*)d_in[1];  // (131328, 64)
    const float* l_coefs    = (const float*)d_in[2];  // (512, 64)
    const float* free_coefs = (const float*)d_in[3];  // (1, 64)
    float* out = (float*)d_out;                       // (2048, 64)

    unsigned short* W = (unsigned short*)d_ws;        // 64*512*512 bf16 = 32 MiB
    float* norm2 = (float*)((char*)d_ws + (size_t)NQ * DIM * DIM * sizeof(unsigned short));

    hsq_zero_kernel<<<1, 64, 0, stream>>>(norm2);
    hsq_expand_kernel<<<dim3(DIM, 16), 256, 0, stream>>>(q_coefs, W, norm2);
    hsq_gemm_kernel<<<dim3(BATCH / MT, NQ), 256, 0, stream>>>(points, W, l_coefs, free_coefs, norm2, out);
}

// Round 2
// 279.464 us; speedup vs baseline: 2.0053x; 2.0053x over previous
//
#include <hip/hip_runtime.h>

// Problem constants (fixed by setup_inputs)
#define DIM 512
#define NQ 64
#define BATCH 2048
#define MT 64            // batch rows per block in GEMM
#define APAD 520         // LDS row stride (bf16 elems) for A tile

typedef __bf16  bf16x8  __attribute__((ext_vector_type(8)));
typedef float   floatx4 __attribute__((ext_vector_type(4)));

static __device__ inline unsigned short f2bf(float f) {
    unsigned int u = __float_as_uint(f);
    unsigned int r = (u + 0x7fffu + ((u >> 16) & 1u)) >> 16;  // RNE
    return (unsigned short)r;
}

__global__ void hsq_zero_kernel(float* p) { p[threadIdx.x] = 0.0f; }

// Expand q_coefs (n_mono, 64) into W[k][e][d] (bf16, d contiguous), fused norm2.
// lane = k  =>  every qc load is a wave-uniform-row, 256B fully-coalesced load.
// Each wave handles one (e, d-run of 32); lane writes its 64B run of W[k][e][*].
__global__ __launch_bounds__(256, 4)
void hsq_expand_kernel(const float* __restrict__ qc,
                       unsigned short* __restrict__ W,
                       float* __restrict__ norm2) {
    const int wid = threadIdx.x >> 6;
    const int k   = threadIdx.x & 63;          // lane = quadric index
    const int task = blockIdx.x * 4 + wid;     // 0..8191
    const int e  = task >> 4;
    const int d0 = (task & 15) * 32;

    float v[32];
#pragma unroll
    for (int s = 0; s < 32; ++s) {
        const int d = d0 + s;
        const int i = d < e ? d : e;
        const int j = d < e ? e : d;
        const int idx = i * DIM - ((i * (i - 1)) >> 1) + (j - i);
        v[s] = qc[(size_t)idx * NQ + k];
    }

    float nacc = 0.0f;                         // norm2: count each monomial once (d>=e)
#pragma unroll
    for (int s = 0; s < 32; ++s) {
        if (d0 + s >= e) nacc += v[s] * v[s];
    }

    unsigned int pk[16];
#pragma unroll
    for (int t = 0; t < 16; ++t) {
        const int da = d0 + 2 * t, db = da + 1;
        const float a = v[2 * t]     * ((da == e) ? 2.0f : 1.41421356237309515f);
        const float b = v[2 * t + 1] * ((db == e) ? 2.0f : 1.41421356237309515f);
        pk[t] = (unsigned)f2bf(a) | ((unsigned)f2bf(b) << 16);
    }
    uint4* dst = reinterpret_cast<uint4*>(W + ((size_t)(k * DIM + e)) * DIM + d0);
#pragma unroll
    for (int t = 0; t < 4; ++t)
        dst[t] = make_uint4(pk[4 * t], pk[4 * t + 1], pk[4 * t + 2], pk[4 * t + 3]);

    __shared__ float part[4][64];
    part[wid][k] = nacc;
    __syncthreads();
    if (threadIdx.x < 64) {
        const float s = part[0][k] + part[1][k] + part[2][k] + part[3][k];
        if (s != 0.0f) atomicAdd(&norm2[k], s);
    }
}

// Main fused kernel: per block = (64 batch rows, one quadric k).
// G = P_tile (64x512) * M_k (512x512) via mfma_f32_16x16x32_bf16,
// epilogue reduces over e to produce scores directly.
__global__ __launch_bounds__(256, 2)
void hsq_gemm_kernel(const float* __restrict__ points,
                     const unsigned short* __restrict__ W,
                     const float* __restrict__ l_coefs,
                     const float* __restrict__ free_coefs,
                     const float* __restrict__ norm2,
                     float* __restrict__ out) {
    const int k  = blockIdx.x;   // 0..63  quadric (x-major => same-XCD blocks share k range)
    const int mb = blockIdx.y;   // 0..31  batch tile
    const int tid  = threadIdx.x;
    const int wid  = tid >> 6;   // 0..3, wave covers e in [wid*128, wid*128+128)
    const int lane = tid & 63;
    const int c    = lane & 15;  // MFMA col / A row index
    const int quad = lane >> 4;  // MFMA k-block / D row-block

    __shared__ unsigned short As[MT * APAD];   // 66560 B, bf16 P tile
    __shared__ float red[4][MT][2];            // per-wave partial (pv, pg) per row

    // ---- Stage A once: 64 rows x 512 cols fp32 -> bf16 LDS (float4 loads) ----
    {
        const float* src = points + (size_t)mb * MT * DIM;
#pragma unroll
        for (int it = 0; it < 32; ++it) {
            const int lin4 = it * 256 + tid;       // over 64*128 float4s
            const int r  = lin4 >> 7;
            const int c4 = lin4 & 127;
            const float4 v = *reinterpret_cast<const float4*>(src + ((size_t)r * DIM + c4 * 4));
            unsigned short* dstp = &As[r * APAD + c4 * 4];
            dstp[0] = f2bf(v.x); dstp[1] = f2bf(v.y);
            dstp[2] = f2bf(v.z); dstp[3] = f2bf(v.w);
        }
    }
    __syncthreads();

    // ---- K-loop: no barriers. A from LDS, B frags direct from global W. ----
    floatx4 acc[4][8];
#pragma unroll
    for (int mt = 0; mt < 4; ++mt)
#pragma unroll
        for (int nt = 0; nt < 8; ++nt)
            acc[mt][nt] = (floatx4){0.f, 0.f, 0.f, 0.f};

    const unsigned short* Wk = W + (size_t)k * DIM * DIM;

    for (int ks = 0; ks < 16; ++ks) {
        const int d0 = ks * 32;
        bf16x8 af[4];
#pragma unroll
        for (int mt = 0; mt < 4; ++mt)
            af[mt] = *reinterpret_cast<const bf16x8*>(&As[(mt * 16 + c) * APAD + d0 + quad * 8]);
        bf16x8 bfr[8];
#pragma unroll
        for (int nt = 0; nt < 8; ++nt) {
            const int e = wid * 128 + nt * 16 + c;
            bfr[nt] = *reinterpret_cast<const bf16x8*>(Wk + (size_t)e * DIM + d0 + quad * 8);
        }
#pragma unroll
        for (int mt = 0; mt < 4; ++mt)
#pragma unroll
            for (int nt = 0; nt < 8; ++nt)
                acc[mt][nt] = __builtin_amdgcn_mfma_f32_16x16x32_bf16(af[mt], bfr[nt], acc[mt][nt], 0, 0, 0);
    }

    // ---- Epilogue: per-row reductions over this wave's 128 e-columns ----
    // pv = sum_e p[b,e]*(0.5*g + l[e,k]);  pg = sum_e (g + l[e,k])^2
#pragma unroll
    for (int mt = 0; mt < 4; ++mt) {
        float pv[4] = {0.f, 0.f, 0.f, 0.f};
        float pg[4] = {0.f, 0.f, 0.f, 0.f};
#pragma unroll
        for (int nt = 0; nt < 8; ++nt) {
            const int e = wid * 128 + nt * 16 + c;
            const float l = l_coefs[e * NQ + k];
            const int rowbase = mb * MT + mt * 16 + quad * 4;
#pragma unroll
            for (int r = 0; r < 4; ++r) {
                const float p = points[(size_t)(rowbase + r) * DIM + e];
                const float g = acc[mt][nt][r];
                pv[r] += p * (0.5f * g + l);
                const float qg = g + l;
                pg[r] += qg * qg;
            }
        }
#pragma unroll
        for (int r = 0; r < 4; ++r) {
#pragma unroll
            for (int off = 1; off < 16; off <<= 1) {
                pv[r] += __shfl_xor(pv[r], off);
                pg[r] += __shfl_xor(pg[r], off);
            }
            if (c == 0) {
                const int row = mt * 16 + quad * 4 + r;
                red[wid][row][0] = pv[r];
                red[wid][row][1] = pg[r];
            }
        }
    }
    __syncthreads();

    if (tid < MT) {
        const int row = tid;
        float v = 0.f, g = 0.f;
#pragma unroll
        for (int w = 0; w < 4; ++w) { v += red[w][row][0]; g += red[w][row][1]; }
        const float vals = fabsf(v + free_coefs[k]);
        const float nrm  = sqrtf(norm2[k]);
        const float sc   = (sqrtf(0.25f * g + vals * nrm) - 0.5f * sqrtf(g)) / nrm;
        out[(size_t)(mb * MT + row) * NQ + k] = sc;
    }
}

extern "C" void kernel_launch(void* const* d_in, const int* in_sizes, int n_in,
                              void* d_out, int out_size, void* d_ws, size_t ws_size,
                              hipStream_t stream) {
    const float* points     = (const float*)d_in[0];  // (2048, 512)
    const float* q_coefs    = (const float*)d_in[1];  // (131328, 64)
    const float* l_coefs    = (const float*)d_in[2];  // (512, 64)
    const float* free_coefs = (const float*)d_in[3];  // (1, 64)
    float* out = (float*)d_out;                       // (2048, 64)

    unsigned short* W = (unsigned short*)d_ws;        // 64*512*512 bf16 = 32 MiB
    float* norm2 = (float*)((char*)d_ws + (size_t)NQ * DIM * DIM * sizeof(unsigned short));

    hsq_zero_kernel<<<1, 64, 0, stream>>>(norm2);
    hsq_expand_kernel<<<dim3(8192 / 4), 256, 0, stream>>>(q_coefs, W, norm2);
    hsq_gemm_kernel<<<dim3(NQ, BATCH / MT), 256, 0, stream>>>(points, W, l_coefs, free_coefs, norm2, out);
}